// Round 12
// baseline (355.444 us; speedup 1.0000x reference)
//
#include <hip/hip_runtime.h>
#include <stdint.h>

#define N_NODES 50000
#define N_EDGES 800000
#define F0 512
#define F1 256
#define F2 128
#define CAP 64   // Poisson(16) in-degree: P(deg>64) ~ 2e-18/node

typedef __attribute__((ext_vector_type(8))) short short8;
typedef __attribute__((ext_vector_type(4))) float float4v;

// ==== JAX threefry2x32, key=(0,42), partitionable, 32-bit draw = x0 ^ x1 ====
__device__ __forceinline__ uint32_t r8_rotl(uint32_t x, int r) {
    return (x << r) | (x >> (32 - r));
}

__device__ __forceinline__ uint32_t r8_bits32(uint32_t idx) {
    const uint32_t ks0 = 0u;
    const uint32_t ks1 = 42u;
    const uint32_t ks2 = 0x1BD11BDAu ^ ks0 ^ ks1;  // 0x1BD11BF0
    uint32_t x0 = ks0;        // c0 = 0
    uint32_t x1 = idx + ks1;  // c1 = idx
#define R8R(r) { x0 += x1; x1 = r8_rotl(x1, (r)); x1 ^= x0; }
    R8R(13) R8R(15) R8R(26) R8R(6)
    x0 += ks1; x1 += ks2 + 1u;
    R8R(17) R8R(29) R8R(16) R8R(24)
    x0 += ks2; x1 += ks0 + 2u;
    R8R(13) R8R(15) R8R(26) R8R(6)
    x0 += ks0; x1 += ks1 + 3u;
    R8R(17) R8R(29) R8R(16) R8R(24)
    x0 += ks1; x1 += ks2 + 4u;
    R8R(13) R8R(15) R8R(26) R8R(6)
    x0 += ks2; x1 += ks0 + 5u;
#undef R8R
    return x0 ^ x1;  // partitionable 32-bit combine
}

__device__ __forceinline__ int r8_keep(uint32_t idx) {
    return (r8_bits32(idx) >> 9) < 0x666667u;  // u < 0.8f, exact integer form
}

__device__ __forceinline__ unsigned short r8_f2bf(float f) {
    uint32_t u = __float_as_uint(f);
    uint32_t r = u + 0x7fffu + ((u >> 16) & 1u);  // RNE
    return (unsigned short)(r >> 16);
}

// ======= graph prep =======
__global__ void r8_detect(const uint32_t* __restrict__ ei, int* __restrict__ flag) {
    int t = threadIdx.x;  // 0..63
    uint32_t v = ei[2 * t + 1] | ei[128 + 2 * t + 1];
    unsigned long long any_nonzero = __ballot(v != 0u);
    if (t == 0) flag[0] = (any_nonzero == 0ull) ? 1 : 0;
}

__global__ void r8_fill(const int* __restrict__ ei, const int* __restrict__ flag,
                        int* __restrict__ cursor, int* __restrict__ bucket) {
    int e = blockIdx.x * 256 + threadIdx.x;
    if (e < N_EDGES) {
        int f = flag[0];  // 0: int32, 1: int64 (read low words)
        int s = ei[(size_t)e << f];
        int d = ei[(size_t)(N_EDGES + e) << f];
        int pos = atomicAdd(&cursor[d], 1);
        if (pos < CAP) bucket[(size_t)d * CAP + pos] = s;
    }
}

__global__ void r8_dinv(const int* __restrict__ cursor, float* __restrict__ dinv) {
    int v = blockIdx.x * 256 + threadIdx.x;
    if (v < N_NODES) dinv[v] = 1.0f / sqrtf((float)(cursor[v] + 1));  // +1 self loop
}

// W1 f32 [512][256] -> W1^T bf16 [256][512]
__global__ void r8_w1t(const float* __restrict__ W1, unsigned short* __restrict__ Bt) {
    int k = blockIdx.x;       // 0..511
    int n = threadIdx.x;      // 0..255
    Bt[(size_t)n * F0 + k] = r8_f2bf(W1[(size_t)k * F1 + n]);
}

// W2 f32 [256][128] -> W2^T bf16 [128][256]
__global__ void r8_w2t(const float* __restrict__ W2, unsigned short* __restrict__ Bt) {
    int k = blockIdx.x;       // 0..255
    int n = threadIdx.x;      // 0..127
    Bt[(size_t)n * F1 + k] = r8_f2bf(W2[(size_t)k * F2 + n]);
}

// ======= bf16 MFMA GEMM1: h1[M,256] = x[M,512] @ W1 =======
// 128x256 FULL-N tile, BK=32, dbuf, depth-2 prefetch. Plateaued at ~64 µs
// across 6 structural variants (latency/barrier/step/occupancy/byte models
// all refuted) — consistent with the small-shape GEMM regime (~205 TF).
#define G1_LDA 40
__global__ __launch_bounds__(512)
void r8_gemm1(const float* __restrict__ A, const unsigned short* __restrict__ Bt,
              unsigned short* __restrict__ C, int M) {
    __shared__ unsigned short As[2][128][G1_LDA];
    __shared__ unsigned short Bs[2][256][G1_LDA];
    const int bm = blockIdx.x * 128;
    const int tid = threadIdx.x;           // 0..511
    const int wave = tid >> 6;             // 0..7
    const int lane = tid & 63;
    const int wm = (wave & 1) * 64;        // 0,64
    const int wn = (wave >> 1) * 64;       // 0,64,128,192
    const int l15 = lane & 15;
    const int quad = lane >> 4;

    const int asr = tid >> 2;              // A staging row 0..127
    const int ask = (tid & 3) * 8;         // A staging col 0/8/16/24 (8 f32)
    const int bsr = tid >> 1;              // B staging row 0..255
    const int bsk = (tid & 1) * 16;        // B staging col 0/16

    float4v acc[4][4];
#pragma unroll
    for (int i = 0; i < 4; ++i)
#pragma unroll
        for (int j = 0; j < 4; ++j) acc[i][j] = (float4v){0.f, 0.f, 0.f, 0.f};

    const int arow = bm + asr;
    const bool avalid = arow < M;
    const float* aptr = A + (size_t)(avalid ? arow : 0) * F0 + ask;
    const unsigned short* bptr = Bt + (size_t)bsr * F0 + bsk;

    float4 apfA[2], apfB[2];
    short8 bpfA[2], bpfB[2];
#pragma unroll
    for (int q = 0; q < 2; ++q) {
        apfA[q] = make_float4(0.f, 0.f, 0.f, 0.f);
        apfB[q] = make_float4(0.f, 0.f, 0.f, 0.f);
    }

    auto load_tile = [&](int kt, float4 (&apf)[2], short8 (&bpf)[2]) {
        const int k0 = kt * 32;
        if (avalid) {
            const float4* ap = (const float4*)(aptr + k0);
            apf[0] = ap[0];
            apf[1] = ap[1];
        }
        bpf[0] = *(const short8*)(bptr + k0);
        bpf[1] = *(const short8*)(bptr + k0 + 8);
    };

    auto write_buf = [&](int buf, const float4 (&apf)[2], const short8 (&bpf)[2]) {
        union { short8 v; unsigned short u[8]; } t;
        t.u[0] = r8_f2bf(apf[0].x); t.u[1] = r8_f2bf(apf[0].y);
        t.u[2] = r8_f2bf(apf[0].z); t.u[3] = r8_f2bf(apf[0].w);
        t.u[4] = r8_f2bf(apf[1].x); t.u[5] = r8_f2bf(apf[1].y);
        t.u[6] = r8_f2bf(apf[1].z); t.u[7] = r8_f2bf(apf[1].w);
        *(short8*)&As[buf][asr][ask] = t.v;
        *(short8*)&Bs[buf][bsr][bsk] = bpf[0];
        *(short8*)&Bs[buf][bsr][bsk + 8] = bpf[1];
    };

    auto compute = [&](int cur) {
        short8 afr[4], bfr[4];
#pragma unroll
        for (int mi = 0; mi < 4; ++mi)
            afr[mi] = *(const short8*)&As[cur][wm + mi * 16 + l15][quad * 8];
#pragma unroll
        for (int ni = 0; ni < 4; ++ni)
            bfr[ni] = *(const short8*)&Bs[cur][wn + ni * 16 + l15][quad * 8];
#pragma unroll
        for (int mi = 0; mi < 4; ++mi)
#pragma unroll
            for (int ni = 0; ni < 4; ++ni)
                acc[mi][ni] = __builtin_amdgcn_mfma_f32_16x16x32_bf16(
                    afr[mi], bfr[ni], acc[mi][ni], 0, 0, 0);
    };

    const int NT = F0 / 32;  // 16 (even)
    load_tile(0, apfA, bpfA);
    write_buf(0, apfA, bpfA);
    load_tile(1, apfB, bpfB);
    __syncthreads();

    for (int kt = 0; kt < NT; kt += 2) {
        if (kt + 2 < NT) load_tile(kt + 2, apfA, bpfA);   // 2 steps ahead
        compute(0);
        write_buf(1, apfB, bpfB);                         // tile kt+1
        __syncthreads();
        if (kt + 3 < NT) load_tile(kt + 3, apfB, bpfB);
        compute(1);
        if (kt + 2 < NT) write_buf(0, apfA, bpfA);        // tile kt+2
        __syncthreads();
    }

    // epilogue: C/D layout col=lane&15, row=quad*4+reg; store bf16
#pragma unroll
    for (int mi = 0; mi < 4; ++mi) {
#pragma unroll
        for (int r = 0; r < 4; ++r) {
            int row = bm + wm + mi * 16 + quad * 4 + r;
            if (row < M) {
                unsigned short* cp = C + (size_t)row * F1 + wn + l15;
#pragma unroll
                for (int ni = 0; ni < 4; ++ni) cp[ni * 16] = r8_f2bf(acc[mi][ni][r]);
            }
        }
    }
}

// ======= FUSED propagation 1 + bias + ReLU + dropout + GEMM2 =======
// 16 nodes per 512-thread block (8 waves, 2 nodes/wave sequential).
// Phase 1: R4-proven shfl-gather aggregation; a1 rows (bf16, same values as
// the old global a1) land in LDS (row pad +8 bf16 -> A-frag reads hit 16
// distinct banks instead of 16-way conflict at stride 512B).
// Phase 2: gemm2 verbatim — per wave one 16-col slice of h2[16][128] via 8x
// mfma_16x16x32_bf16 over K=256 in the same K-order -> h2 bit-identical.
// Saves a1's 25.6MB write + 25.6MB read and the gemm2 dispatch.
#define P1_LDA 264   // 256 + 8 pad (bf16)
__global__ __launch_bounds__(512)
void r8_prop1g2(const unsigned short* __restrict__ h1, const int* __restrict__ bucket,
                const int* __restrict__ deg, const float* __restrict__ dinv,
                const float* __restrict__ b1, const unsigned short* __restrict__ w2t,
                unsigned short* __restrict__ h2) {
    __shared__ unsigned short a1s[16][P1_LDA];
    const int tid = threadIdx.x;
    const int wave = tid >> 6;        // 0..7
    const int lane = tid & 63;
    const int nbase = blockIdx.x * 16;

    // ---- phase 1: aggregate + bias + ReLU + dropout, 2 nodes per wave ----
    for (int i = 0; i < 2; ++i) {
        const int lrow = wave * 2 + i;        // 0..15
        const int v = nbase + lrow;
        const float dv = dinv[v];
        int cnt = deg[v]; if (cnt > CAP) cnt = CAP;

        int s_l = 0; float w_l = 0.f;
        if (lane < cnt) {
            s_l = bucket[(size_t)v * CAP + lane];
            w_l = dinv[s_l] * dv;
        }

        const unsigned short* hrow = h1 + (size_t)lane * 4;
        uint2 hq = *(const uint2*)(h1 + (size_t)v * F1 + lane * 4);
        const float w0 = dv * dv;
        float ax = __uint_as_float(hq.x << 16) * w0;
        float ay = __uint_as_float(hq.x & 0xffff0000u) * w0;
        float az = __uint_as_float(hq.y << 16) * w0;
        float aw = __uint_as_float(hq.y & 0xffff0000u) * w0;

        for (int j = 0; j < cnt; j += 8) {
            int   s[8];
            float w[8];
#pragma unroll
            for (int u = 0; u < 8; ++u) {
                s[u] = __shfl(s_l, j + u);
                w[u] = __shfl(w_l, j + u);
            }
            uint2 r[8];
#pragma unroll
            for (int u = 0; u < 8; ++u)
                r[u] = *(const uint2*)(hrow + (size_t)s[u] * F1);
#pragma unroll
            for (int u = 0; u < 8; ++u) {
                ax += __uint_as_float(r[u].x << 16) * w[u];
                ay += __uint_as_float(r[u].x & 0xffff0000u) * w[u];
                az += __uint_as_float(r[u].y << 16) * w[u];
                aw += __uint_as_float(r[u].y & 0xffff0000u) * w[u];
            }
        }

        float4 bb = *(const float4*)(b1 + lane * 4);
        ax = fmaxf(ax + bb.x, 0.f);
        ay = fmaxf(ay + bb.y, 0.f);
        az = fmaxf(az + bb.z, 0.f);
        aw = fmaxf(aw + bb.w, 0.f);
        uint32_t idx = (uint32_t)v * F1 + (uint32_t)lane * 4;
        ax = r8_keep(idx + 0) ? ax * 1.25f : 0.0f;
        ay = r8_keep(idx + 1) ? ay * 1.25f : 0.0f;
        az = r8_keep(idx + 2) ? az * 1.25f : 0.0f;
        aw = r8_keep(idx + 3) ? aw * 1.25f : 0.0f;
        uint2 st;
        st.x = (uint32_t)r8_f2bf(ax) | ((uint32_t)r8_f2bf(ay) << 16);
        st.y = (uint32_t)r8_f2bf(az) | ((uint32_t)r8_f2bf(aw) << 16);
        *(uint2*)&a1s[lrow][lane * 4] = st;   // 2-way bank alias (free)
    }

    __syncthreads();

    // ---- phase 2: h2[16][128] = a1s[16][256] @ W2, one 16-col slice/wave ----
    const int l15 = lane & 15;
    const int quad = lane >> 4;
    float4v acc = (float4v){0.f, 0.f, 0.f, 0.f};
    const unsigned short* bp = w2t + (size_t)(wave * 16 + l15) * F1 + quad * 8;
#pragma unroll
    for (int k = 0; k < F1; k += 32) {
        short8 afr = *(const short8*)&a1s[l15][k + quad * 8];
        short8 bfr = *(const short8*)(bp + k);
        acc = __builtin_amdgcn_mfma_f32_16x16x32_bf16(afr, bfr, acc, 0, 0, 0);
    }
    // C/D layout: row = quad*4 + r (0..15), col = wave*16 + l15
#pragma unroll
    for (int r = 0; r < 4; ++r) {
        h2[(size_t)(nbase + quad * 4 + r) * F2 + wave * 16 + l15] = r8_f2bf(acc[r]);
    }
}

// ======= propagation 2 + bias + softmax (bf16 gather, f32 accum) =======
__global__ __launch_bounds__(256)
void r8_prop2(const unsigned short* __restrict__ h2, const int* __restrict__ bucket,
              const int* __restrict__ deg, const float* __restrict__ dinv,
              const float* __restrict__ b2, float* __restrict__ out) {
    const int v = (blockIdx.x << 2) + (threadIdx.x >> 6);
    const int lane = threadIdx.x & 63;
    const float dv = dinv[v];
    int cnt = deg[v]; if (cnt > CAP) cnt = CAP;

    int s_l = 0; float w_l = 0.f;
    if (lane < cnt) {
        s_l = bucket[(size_t)v * CAP + lane];
        w_l = dinv[s_l] * dv;
    }

    const unsigned short* hrow = h2 + (size_t)lane * 2;
    uint32_t hq = *(const uint32_t*)(h2 + (size_t)v * F2 + lane * 2);
    const float w0 = dv * dv;
    float ax = __uint_as_float(hq << 16) * w0;
    float ay = __uint_as_float(hq & 0xffff0000u) * w0;

    for (int j = 0; j < cnt; j += 8) {
        int   s[8];
        float w[8];
#pragma unroll
        for (int u = 0; u < 8; ++u) {
            s[u] = __shfl(s_l, j + u);
            w[u] = __shfl(w_l, j + u);
        }
        uint32_t r[8];
#pragma unroll
        for (int u = 0; u < 8; ++u)
            r[u] = *(const uint32_t*)(hrow + (size_t)s[u] * F2);
#pragma unroll
        for (int u = 0; u < 8; ++u) {
            ax += __uint_as_float(r[u] << 16) * w[u];
            ay += __uint_as_float(r[u] & 0xffff0000u) * w[u];
        }
    }

    float2 bb = *(const float2*)(b2 + lane * 2);
    ax += bb.x; ay += bb.y;
    float m = fmaxf(ax, ay);
#pragma unroll
    for (int o = 32; o >= 1; o >>= 1) m = fmaxf(m, __shfl_xor(m, o, 64));
    float ex = expf(ax - m), ey = expf(ay - m);
    float s = ex + ey;
#pragma unroll
    for (int o = 32; o >= 1; o >>= 1) s += __shfl_xor(s, o, 64);
    float inv = 1.0f / s;
    *(float2*)(out + (size_t)v * F2 + lane * 2) = make_float2(ex * inv, ey * inv);
}

// ======= launch =======
extern "C" void kernel_launch(void* const* d_in, const int* in_sizes, int n_in,
                              void* d_out, int out_size, void* d_ws, size_t ws_size,
                              hipStream_t stream) {
    const float* x  = (const float*)d_in[0];
    const int*   ei = (const int*)d_in[1];
    const float* W1 = (const float*)d_in[2];
    const float* b1 = (const float*)d_in[3];
    const float* W2 = (const float*)d_in[4];
    const float* b2 = (const float*)d_in[5];
    float* out = (float*)d_out;

    char* ws = (char*)d_ws;
    size_t o = 0;
    auto alloc = [&](size_t bytes) -> char* {
        char* p = ws + o;
        o += (bytes + 511) & ~(size_t)511;
        return p;
    };
    int*            flag   = (int*)           alloc(4);
    int*            cursor = (int*)           alloc((size_t)N_NODES * 4);
    float*          dinv   = (float*)         alloc((size_t)N_NODES * 4);
    int*            bucket = (int*)           alloc((size_t)N_NODES * CAP * 4);
    unsigned short* w1t    = (unsigned short*)alloc((size_t)F1 * F0 * 2);
    unsigned short* w2t    = (unsigned short*)alloc((size_t)F2 * F1 * 2);
    unsigned short* h1     = (unsigned short*)alloc((size_t)N_NODES * F1 * 2);  // bf16
    unsigned short* h2     = (unsigned short*)alloc((size_t)N_NODES * F2 * 2);  // bf16

    hipMemsetAsync(cursor, 0, (size_t)N_NODES * 4, stream);  // stream-ordered, capturable
    r8_detect<<<1, 64, 0, stream>>>((const uint32_t*)ei, flag);
    r8_fill<<<(N_EDGES + 255) / 256, 256, 0, stream>>>(ei, flag, cursor, bucket);
    r8_dinv<<<(N_NODES + 255) / 256, 256, 0, stream>>>(cursor, dinv);
    r8_w1t<<<F0, F1, 0, stream>>>(W1, w1t);
    r8_w2t<<<F1, F2, 0, stream>>>(W2, w2t);

    r8_gemm1<<<(N_NODES + 127) / 128, 512, 0, stream>>>(x, w1t, h1, N_NODES);

    r8_prop1g2<<<N_NODES / 16, 512, 0, stream>>>(h1, bucket, cursor, dinv, b1, w2t, h2);

    r8_prop2<<<N_NODES / 4, 256, 0, stream>>>(h2, bucket, cursor, dinv, b2, out);
}

// Round 13
// 341.502 us; speedup vs baseline: 1.0408x; 1.0408x over previous
//
#include <hip/hip_runtime.h>
#include <stdint.h>

#define N_NODES 50000
#define N_EDGES 800000
#define F0 512
#define F1 256
#define F2 128
#define CAP 64   // Poisson(16) in-degree: P(deg>64) ~ 2e-18/node

typedef __attribute__((ext_vector_type(8))) short short8;
typedef __attribute__((ext_vector_type(4))) float float4v;

// ==== JAX threefry2x32, key=(0,42), partitionable, 32-bit draw = x0 ^ x1 ====
__device__ __forceinline__ uint32_t r8_rotl(uint32_t x, int r) {
    return (x << r) | (x >> (32 - r));
}

__device__ __forceinline__ uint32_t r8_bits32(uint32_t idx) {
    const uint32_t ks0 = 0u;
    const uint32_t ks1 = 42u;
    const uint32_t ks2 = 0x1BD11BDAu ^ ks0 ^ ks1;  // 0x1BD11BF0
    uint32_t x0 = ks0;        // c0 = 0
    uint32_t x1 = idx + ks1;  // c1 = idx
#define R8R(r) { x0 += x1; x1 = r8_rotl(x1, (r)); x1 ^= x0; }
    R8R(13) R8R(15) R8R(26) R8R(6)
    x0 += ks1; x1 += ks2 + 1u;
    R8R(17) R8R(29) R8R(16) R8R(24)
    x0 += ks2; x1 += ks0 + 2u;
    R8R(13) R8R(15) R8R(26) R8R(6)
    x0 += ks0; x1 += ks1 + 3u;
    R8R(17) R8R(29) R8R(16) R8R(24)
    x0 += ks1; x1 += ks2 + 4u;
    R8R(13) R8R(15) R8R(26) R8R(6)
    x0 += ks2; x1 += ks0 + 5u;
#undef R8R
    return x0 ^ x1;  // partitionable 32-bit combine
}

__device__ __forceinline__ int r8_keep(uint32_t idx) {
    return (r8_bits32(idx) >> 9) < 0x666667u;  // u < 0.8f, exact integer form
}

__device__ __forceinline__ unsigned short r8_f2bf(float f) {
    uint32_t u = __float_as_uint(f);
    uint32_t r = u + 0x7fffu + ((u >> 16) & 1u);  // RNE
    return (unsigned short)(r >> 16);
}

// ======= graph prep =======
__global__ void r8_detect(const uint32_t* __restrict__ ei, int* __restrict__ flag) {
    int t = threadIdx.x;  // 0..63
    uint32_t v = ei[2 * t + 1] | ei[128 + 2 * t + 1];
    unsigned long long any_nonzero = __ballot(v != 0u);
    if (t == 0) flag[0] = (any_nonzero == 0ull) ? 1 : 0;
}

__global__ void r8_fill(const int* __restrict__ ei, const int* __restrict__ flag,
                        int* __restrict__ cursor, int* __restrict__ bucket) {
    int e = blockIdx.x * 256 + threadIdx.x;
    if (e < N_EDGES) {
        int f = flag[0];  // 0: int32, 1: int64 (read low words)
        int s = ei[(size_t)e << f];
        int d = ei[(size_t)(N_EDGES + e) << f];
        int pos = atomicAdd(&cursor[d], 1);
        if (pos < CAP) bucket[(size_t)d * CAP + pos] = s;
    }
}

__global__ void r8_dinv(const int* __restrict__ cursor, float* __restrict__ dinv) {
    int v = blockIdx.x * 256 + threadIdx.x;
    if (v < N_NODES) dinv[v] = 1.0f / sqrtf((float)(cursor[v] + 1));  // +1 self loop
}

// W1 f32 [512][256] -> W1^T bf16 [256][512]
__global__ void r8_w1t(const float* __restrict__ W1, unsigned short* __restrict__ Bt) {
    int k = blockIdx.x;       // 0..511
    int n = threadIdx.x;      // 0..255
    Bt[(size_t)n * F0 + k] = r8_f2bf(W1[(size_t)k * F1 + n]);
}

// W2 f32 [256][128] -> W2^T bf16 [128][256]
__global__ void r8_w2t(const float* __restrict__ W2, unsigned short* __restrict__ Bt) {
    int k = blockIdx.x;       // 0..255
    int n = threadIdx.x;      // 0..127
    Bt[(size_t)n * F1 + k] = r8_f2bf(W2[(size_t)k * F2 + n]);
}

// ======= bf16 MFMA GEMM1: h1[M,256] = x[M,512] @ W1 =======
// 128x256 FULL-N tile, BK=32, dbuf, depth-2 prefetch. Plateaued at ~64 µs
// across 6 structural variants (latency/barrier/step/occupancy/byte models
// all refuted) — consistent with the small-shape GEMM regime (~205 TF).
#define G1_LDA 40
__global__ __launch_bounds__(512)
void r8_gemm1(const float* __restrict__ A, const unsigned short* __restrict__ Bt,
              unsigned short* __restrict__ C, int M) {
    __shared__ unsigned short As[2][128][G1_LDA];
    __shared__ unsigned short Bs[2][256][G1_LDA];
    const int bm = blockIdx.x * 128;
    const int tid = threadIdx.x;           // 0..511
    const int wave = tid >> 6;             // 0..7
    const int lane = tid & 63;
    const int wm = (wave & 1) * 64;        // 0,64
    const int wn = (wave >> 1) * 64;       // 0,64,128,192
    const int l15 = lane & 15;
    const int quad = lane >> 4;

    const int asr = tid >> 2;              // A staging row 0..127
    const int ask = (tid & 3) * 8;         // A staging col 0/8/16/24 (8 f32)
    const int bsr = tid >> 1;              // B staging row 0..255
    const int bsk = (tid & 1) * 16;        // B staging col 0/16

    float4v acc[4][4];
#pragma unroll
    for (int i = 0; i < 4; ++i)
#pragma unroll
        for (int j = 0; j < 4; ++j) acc[i][j] = (float4v){0.f, 0.f, 0.f, 0.f};

    const int arow = bm + asr;
    const bool avalid = arow < M;
    const float* aptr = A + (size_t)(avalid ? arow : 0) * F0 + ask;
    const unsigned short* bptr = Bt + (size_t)bsr * F0 + bsk;

    float4 apfA[2], apfB[2];
    short8 bpfA[2], bpfB[2];
#pragma unroll
    for (int q = 0; q < 2; ++q) {
        apfA[q] = make_float4(0.f, 0.f, 0.f, 0.f);
        apfB[q] = make_float4(0.f, 0.f, 0.f, 0.f);
    }

    auto load_tile = [&](int kt, float4 (&apf)[2], short8 (&bpf)[2]) {
        const int k0 = kt * 32;
        if (avalid) {
            const float4* ap = (const float4*)(aptr + k0);
            apf[0] = ap[0];
            apf[1] = ap[1];
        }
        bpf[0] = *(const short8*)(bptr + k0);
        bpf[1] = *(const short8*)(bptr + k0 + 8);
    };

    auto write_buf = [&](int buf, const float4 (&apf)[2], const short8 (&bpf)[2]) {
        union { short8 v; unsigned short u[8]; } t;
        t.u[0] = r8_f2bf(apf[0].x); t.u[1] = r8_f2bf(apf[0].y);
        t.u[2] = r8_f2bf(apf[0].z); t.u[3] = r8_f2bf(apf[0].w);
        t.u[4] = r8_f2bf(apf[1].x); t.u[5] = r8_f2bf(apf[1].y);
        t.u[6] = r8_f2bf(apf[1].z); t.u[7] = r8_f2bf(apf[1].w);
        *(short8*)&As[buf][asr][ask] = t.v;
        *(short8*)&Bs[buf][bsr][bsk] = bpf[0];
        *(short8*)&Bs[buf][bsr][bsk + 8] = bpf[1];
    };

    auto compute = [&](int cur) {
        short8 afr[4], bfr[4];
#pragma unroll
        for (int mi = 0; mi < 4; ++mi)
            afr[mi] = *(const short8*)&As[cur][wm + mi * 16 + l15][quad * 8];
#pragma unroll
        for (int ni = 0; ni < 4; ++ni)
            bfr[ni] = *(const short8*)&Bs[cur][wn + ni * 16 + l15][quad * 8];
#pragma unroll
        for (int mi = 0; mi < 4; ++mi)
#pragma unroll
            for (int ni = 0; ni < 4; ++ni)
                acc[mi][ni] = __builtin_amdgcn_mfma_f32_16x16x32_bf16(
                    afr[mi], bfr[ni], acc[mi][ni], 0, 0, 0);
    };

    const int NT = F0 / 32;  // 16 (even)
    load_tile(0, apfA, bpfA);
    write_buf(0, apfA, bpfA);
    load_tile(1, apfB, bpfB);
    __syncthreads();

    for (int kt = 0; kt < NT; kt += 2) {
        if (kt + 2 < NT) load_tile(kt + 2, apfA, bpfA);   // 2 steps ahead
        compute(0);
        write_buf(1, apfB, bpfB);                         // tile kt+1
        __syncthreads();
        if (kt + 3 < NT) load_tile(kt + 3, apfB, bpfB);
        compute(1);
        if (kt + 2 < NT) write_buf(0, apfA, bpfA);        // tile kt+2
        __syncthreads();
    }

    // epilogue: C/D layout col=lane&15, row=quad*4+reg; store bf16
#pragma unroll
    for (int mi = 0; mi < 4; ++mi) {
#pragma unroll
        for (int r = 0; r < 4; ++r) {
            int row = bm + wm + mi * 16 + quad * 4 + r;
            if (row < M) {
                unsigned short* cp = C + (size_t)row * F1 + wn + l15;
#pragma unroll
                for (int ni = 0; ni < 4; ++ni) cp[ni * 16] = r8_f2bf(acc[mi][ni][r]);
            }
        }
    }
}

// ======= bf16 MFMA GEMM2: h2[M,128] = a1[M,256] @ W2 =======
// 64x128 tile (full N), BK=32, double-buffered, depth-2 prefetch.
// Kept SEPARATE from prop1: fusing (R12) barrier-coupled 16 nodes and
// converted mean gather cost into max-over-16 cost (−28 µs regression).
#define G2_LDA 40
__global__ __launch_bounds__(256)
void r8_gemm2(const unsigned short* __restrict__ A, const unsigned short* __restrict__ Bt,
              unsigned short* __restrict__ C, int M) {
    __shared__ unsigned short As[2][64][G2_LDA];
    __shared__ unsigned short Bs[2][128][G2_LDA];
    const int bm = blockIdx.x * 64;
    const int tid = threadIdx.x;
    const int wave = tid >> 6;
    const int lane = tid & 63;
    const int wm = (wave & 1) * 32;
    const int wn = (wave >> 1) * 64;
    const int l15 = lane & 15;
    const int quad = lane >> 4;

    const int asr = tid >> 2;             // A staging row 0..63
    const int ask = (tid & 3) * 8;        // A staging col 0/8/16/24
    const int bsr = tid >> 1;             // B staging row 0..127
    const int bsk = (tid & 1) * 16;       // B staging col 0/16

    float4v acc[2][4];
#pragma unroll
    for (int i = 0; i < 2; ++i)
#pragma unroll
        for (int j = 0; j < 4; ++j) acc[i][j] = (float4v){0.f, 0.f, 0.f, 0.f};

    const int arow = bm + asr;
    const bool avalid = arow < M;
    const unsigned short* aptr = A + (size_t)(avalid ? arow : 0) * F1 + ask;
    const unsigned short* bptr = Bt + (size_t)bsr * F1 + bsk;

    short8 apfA = (short8){0,0,0,0,0,0,0,0}, apfB = (short8){0,0,0,0,0,0,0,0};
    short8 bpfA[2], bpfB[2];

    auto load_tile = [&](int kt, short8& apf, short8 (&bpf)[2]) {
        const int k0 = kt * 32;
        if (avalid) apf = *(const short8*)(aptr + k0);
        bpf[0] = *(const short8*)(bptr + k0);
        bpf[1] = *(const short8*)(bptr + k0 + 8);
    };

    auto write_buf = [&](int buf, const short8& apf, const short8 (&bpf)[2]) {
        *(short8*)&As[buf][asr][ask] = apf;
        *(short8*)&Bs[buf][bsr][bsk] = bpf[0];
        *(short8*)&Bs[buf][bsr][bsk + 8] = bpf[1];
    };

    auto compute = [&](int cur) {
        short8 afr[2], bfr[4];
#pragma unroll
        for (int mi = 0; mi < 2; ++mi)
            afr[mi] = *(const short8*)&As[cur][wm + mi * 16 + l15][quad * 8];
#pragma unroll
        for (int ni = 0; ni < 4; ++ni)
            bfr[ni] = *(const short8*)&Bs[cur][wn + ni * 16 + l15][quad * 8];
#pragma unroll
        for (int mi = 0; mi < 2; ++mi)
#pragma unroll
            for (int ni = 0; ni < 4; ++ni)
                acc[mi][ni] = __builtin_amdgcn_mfma_f32_16x16x32_bf16(
                    afr[mi], bfr[ni], acc[mi][ni], 0, 0, 0);
    };

    const int NT = F1 / 32;  // 8 (even)
    load_tile(0, apfA, bpfA);
    write_buf(0, apfA, bpfA);
    load_tile(1, apfB, bpfB);
    __syncthreads();

    for (int kt = 0; kt < NT; kt += 2) {
        if (kt + 2 < NT) load_tile(kt + 2, apfA, bpfA);
        compute(0);
        write_buf(1, apfB, bpfB);
        __syncthreads();
        if (kt + 3 < NT) load_tile(kt + 3, apfB, bpfB);
        compute(1);
        if (kt + 2 < NT) write_buf(0, apfA, bpfA);
        __syncthreads();
    }

#pragma unroll
    for (int mi = 0; mi < 2; ++mi) {
#pragma unroll
        for (int r = 0; r < 4; ++r) {
            int row = bm + wm + mi * 16 + quad * 4 + r;
            if (row < M) {
                unsigned short* cp = C + (size_t)row * F2 + wn + l15;
#pragma unroll
                for (int ni = 0; ni < 4; ++ni) cp[ni * 16] = r8_f2bf(acc[mi][ni][r]);
            }
        }
    }
}

// ======= propagation 1 + bias + ReLU + dropout (bf16 gather, f32 accum, bf16 out) =======
// Known-best R4 shfl structure: 4 independent nodes per block (no cross-node
// barrier — R12 showed barrier-coupling converts mean gather cost to max).
// Neighbor ids + weights preloaded into lanes, broadcast via shfl; 8
// independent 8B row-gathers in flight per round. Threefry inline (hides
// under gather latency; hoisting regressed).
__global__ __launch_bounds__(256)
void r8_prop1(const unsigned short* __restrict__ h1, const int* __restrict__ bucket,
              const int* __restrict__ deg, const float* __restrict__ dinv,
              const float* __restrict__ b1, unsigned short* __restrict__ a1) {
    const int v = (blockIdx.x << 2) + (threadIdx.x >> 6);
    const int lane = threadIdx.x & 63;
    const float dv = dinv[v];
    int cnt = deg[v]; if (cnt > CAP) cnt = CAP;

    int s_l = 0; float w_l = 0.f;
    if (lane < cnt) {
        s_l = bucket[(size_t)v * CAP + lane];
        w_l = dinv[s_l] * dv;
    }

    const unsigned short* hrow = h1 + (size_t)lane * 4;
    uint2 hq = *(const uint2*)(h1 + (size_t)v * F1 + lane * 4);
    const float w0 = dv * dv;
    float ax = __uint_as_float(hq.x << 16) * w0;
    float ay = __uint_as_float(hq.x & 0xffff0000u) * w0;
    float az = __uint_as_float(hq.y << 16) * w0;
    float aw = __uint_as_float(hq.y & 0xffff0000u) * w0;

    for (int j = 0; j < cnt; j += 8) {
        int   s[8];
        float w[8];
#pragma unroll
        for (int u = 0; u < 8; ++u) {
            s[u] = __shfl(s_l, j + u);
            w[u] = __shfl(w_l, j + u);
        }
        uint2 r[8];
#pragma unroll
        for (int u = 0; u < 8; ++u)
            r[u] = *(const uint2*)(hrow + (size_t)s[u] * F1);
#pragma unroll
        for (int u = 0; u < 8; ++u) {
            ax += __uint_as_float(r[u].x << 16) * w[u];
            ay += __uint_as_float(r[u].x & 0xffff0000u) * w[u];
            az += __uint_as_float(r[u].y << 16) * w[u];
            aw += __uint_as_float(r[u].y & 0xffff0000u) * w[u];
        }
    }

    float4 bb = *(const float4*)(b1 + lane * 4);
    ax = fmaxf(ax + bb.x, 0.f);
    ay = fmaxf(ay + bb.y, 0.f);
    az = fmaxf(az + bb.z, 0.f);
    aw = fmaxf(aw + bb.w, 0.f);
    uint32_t idx = (uint32_t)v * F1 + (uint32_t)lane * 4;
    ax = r8_keep(idx + 0) ? ax * 1.25f : 0.0f;
    ay = r8_keep(idx + 1) ? ay * 1.25f : 0.0f;
    az = r8_keep(idx + 2) ? az * 1.25f : 0.0f;
    aw = r8_keep(idx + 3) ? aw * 1.25f : 0.0f;
    uint2 st;
    st.x = (uint32_t)r8_f2bf(ax) | ((uint32_t)r8_f2bf(ay) << 16);
    st.y = (uint32_t)r8_f2bf(az) | ((uint32_t)r8_f2bf(aw) << 16);
    *(uint2*)(a1 + (size_t)v * F1 + lane * 4) = st;
}

// ======= propagation 2 + bias + softmax (bf16 gather, f32 accum) =======
__global__ __launch_bounds__(256)
void r8_prop2(const unsigned short* __restrict__ h2, const int* __restrict__ bucket,
              const int* __restrict__ deg, const float* __restrict__ dinv,
              const float* __restrict__ b2, float* __restrict__ out) {
    const int v = (blockIdx.x << 2) + (threadIdx.x >> 6);
    const int lane = threadIdx.x & 63;
    const float dv = dinv[v];
    int cnt = deg[v]; if (cnt > CAP) cnt = CAP;

    int s_l = 0; float w_l = 0.f;
    if (lane < cnt) {
        s_l = bucket[(size_t)v * CAP + lane];
        w_l = dinv[s_l] * dv;
    }

    const unsigned short* hrow = h2 + (size_t)lane * 2;
    uint32_t hq = *(const uint32_t*)(h2 + (size_t)v * F2 + lane * 2);
    const float w0 = dv * dv;
    float ax = __uint_as_float(hq << 16) * w0;
    float ay = __uint_as_float(hq & 0xffff0000u) * w0;

    for (int j = 0; j < cnt; j += 8) {
        int   s[8];
        float w[8];
#pragma unroll
        for (int u = 0; u < 8; ++u) {
            s[u] = __shfl(s_l, j + u);
            w[u] = __shfl(w_l, j + u);
        }
        uint32_t r[8];
#pragma unroll
        for (int u = 0; u < 8; ++u)
            r[u] = *(const uint32_t*)(hrow + (size_t)s[u] * F2);
#pragma unroll
        for (int u = 0; u < 8; ++u) {
            ax += __uint_as_float(r[u] << 16) * w[u];
            ay += __uint_as_float(r[u] & 0xffff0000u) * w[u];
        }
    }

    float2 bb = *(const float2*)(b2 + lane * 2);
    ax += bb.x; ay += bb.y;
    float m = fmaxf(ax, ay);
#pragma unroll
    for (int o = 32; o >= 1; o >>= 1) m = fmaxf(m, __shfl_xor(m, o, 64));
    float ex = expf(ax - m), ey = expf(ay - m);
    float s = ex + ey;
#pragma unroll
    for (int o = 32; o >= 1; o >>= 1) s += __shfl_xor(s, o, 64);
    float inv = 1.0f / s;
    *(float2*)(out + (size_t)v * F2 + lane * 2) = make_float2(ex * inv, ey * inv);
}

// ======= launch =======
extern "C" void kernel_launch(void* const* d_in, const int* in_sizes, int n_in,
                              void* d_out, int out_size, void* d_ws, size_t ws_size,
                              hipStream_t stream) {
    const float* x  = (const float*)d_in[0];
    const int*   ei = (const int*)d_in[1];
    const float* W1 = (const float*)d_in[2];
    const float* b1 = (const float*)d_in[3];
    const float* W2 = (const float*)d_in[4];
    const float* b2 = (const float*)d_in[5];
    float* out = (float*)d_out;

    char* ws = (char*)d_ws;
    size_t o = 0;
    auto alloc = [&](size_t bytes) -> char* {
        char* p = ws + o;
        o += (bytes + 511) & ~(size_t)511;
        return p;
    };
    int*            flag   = (int*)           alloc(4);
    int*            cursor = (int*)           alloc((size_t)N_NODES * 4);
    float*          dinv   = (float*)         alloc((size_t)N_NODES * 4);
    int*            bucket = (int*)           alloc((size_t)N_NODES * CAP * 4);
    unsigned short* w1t    = (unsigned short*)alloc((size_t)F1 * F0 * 2);
    unsigned short* w2t    = (unsigned short*)alloc((size_t)F2 * F1 * 2);
    unsigned short* h1     = (unsigned short*)alloc((size_t)N_NODES * F1 * 2);  // bf16
    unsigned short* a1     = (unsigned short*)alloc((size_t)N_NODES * F1 * 2);  // bf16
    unsigned short* h2     = (unsigned short*)alloc((size_t)N_NODES * F2 * 2);  // bf16

    hipMemsetAsync(cursor, 0, (size_t)N_NODES * 4, stream);  // stream-ordered, capturable
    r8_detect<<<1, 64, 0, stream>>>((const uint32_t*)ei, flag);
    r8_fill<<<(N_EDGES + 255) / 256, 256, 0, stream>>>(ei, flag, cursor, bucket);
    r8_dinv<<<(N_NODES + 255) / 256, 256, 0, stream>>>(cursor, dinv);
    r8_w1t<<<F0, F1, 0, stream>>>(W1, w1t);
    r8_w2t<<<F1, F2, 0, stream>>>(W2, w2t);

    r8_gemm1<<<(N_NODES + 127) / 128, 512, 0, stream>>>(x, w1t, h1, N_NODES);

    r8_prop1<<<N_NODES / 4, 256, 0, stream>>>(h1, bucket, cursor, dinv, b1, a1);

    r8_gemm2<<<(N_NODES + 63) / 64, 256, 0, stream>>>(a1, w2t, h2, N_NODES);

    r8_prop2<<<N_NODES / 4, 256, 0, stream>>>(h2, bucket, cursor, dinv, b2, out);
}